// Round 1
// baseline (69.133 us; speedup 1.0000x reference)
//
#include <hip/hip_runtime.h>

// ---------------------------------------------------------------------------
// QConv2d collapses algebraically:
//   U = u0 (x) V  with V = u1(x)u2(x)u3  (wire 0 = MSB)
//   <psi| sigma_0 (x) I8 |psi> with psi = U P a  (a real, P = CNOT-ring perm)
//     = a^T [ P^T ( Re(u0^† sigma u0) (x) I8 ) P ] a
//     = alpha*c00 + beta*c11 + gamma*c01    (per (kernel, pauli))
// where c00 = sum_{i: f(i)<8} p_i^2, c11 = rest, c01 = sum_d p_{g(d)} p_{g(d+8)}
// (f = ring map, g = f^{-1}), and a = p/||p|| so divide by n = ||p||^2.
// ---------------------------------------------------------------------------

struct cplx { float re, im; };
__host__ __device__ inline cplx cmul(cplx a, cplx b){ return {a.re*b.re - a.im*b.im, a.re*b.im + a.im*b.re}; }
__host__ __device__ inline cplx cconj(cplx a){ return {a.re, -a.im}; }
__host__ __device__ inline cplx cadd(cplx a, cplx b){ return {a.re+b.re, a.im+b.im}; }

// CNOT ring map on basis index (wire 0 = MSB), exactly mirrors reference.
__host__ __device__ constexpr int ringf(int i){
    int s = i;
    for (int w = 0; w < 4; ++w){
        int c = w, t = (w + 1) & 3;
        if ((s >> (3 - c)) & 1) s ^= 1 << (3 - t);
    }
    return s;
}

// One-warp setup: thread t in [0,12) computes (alpha,beta,gamma) for
// (k = t/3, pauli o = t%3) with explicit complex 2x2 arithmetic.
__global__ void coef_kernel(const float* __restrict__ w, float* __restrict__ coef){
    int t = threadIdx.x;
    if (t >= 12) return;
    int k = t / 3, o = t - 3 * (t / 3);
    float th = w[k*12 + 0], ph = w[k*12 + 1], om = w[k*12 + 2];
    float c = cosf(th * 0.5f), s = sinf(th * 0.5f);
    cplx u[2][2];
    u[0][0] = { c, 0.f };
    u[0][1] = { -cosf(om) * s, -sinf(om) * s };
    u[1][0] = {  cosf(ph) * s,  sinf(ph) * s };
    u[1][1] = {  cosf(ph + om) * c, sinf(ph + om) * c };
    cplx sig[2][2];
    if (o == 0){      sig[0][0]={0,0}; sig[0][1]={1,0};  sig[1][0]={1,0}; sig[1][1]={0,0}; }   // X
    else if (o == 1){ sig[0][0]={0,0}; sig[0][1]={0,-1}; sig[1][0]={0,1}; sig[1][1]={0,0}; }   // Y
    else {            sig[0][0]={1,0}; sig[0][1]={0,0};  sig[1][0]={0,0}; sig[1][1]={-1,0}; }  // Z
    // A = u^dag sig u
    cplx A[2][2];
    for (int a = 0; a < 2; ++a)
        for (int b = 0; b < 2; ++b){
            cplx acc = {0.f, 0.f};
            for (int ss = 0; ss < 2; ++ss)
                for (int tt = 0; tt < 2; ++tt)
                    acc = cadd(acc, cmul(cmul(cconj(u[ss][a]), sig[ss][tt]), u[tt][b]));
            A[a][b] = acc;
        }
    coef[t*3 + 0] = A[0][0].re;
    coef[t*3 + 1] = A[1][1].re;
    coef[t*3 + 2] = 2.f * A[0][1].re;
}

// One thread per patch. B*961 threads; 961 = 31*31 output positions.
__global__ __launch_bounds__(256) void qconv_kernel(
    const float* __restrict__ x, const float* __restrict__ coef,
    float* __restrict__ out, int B)
{
    __shared__ float scoef[36];
    if (threadIdx.x < 36) scoef[threadIdx.x] = coef[threadIdx.x];
    __syncthreads();

    int pid = blockIdx.x * 256 + threadIdx.x;
    if (pid >= B * 961) return;
    int b  = pid / 961;
    int l  = pid - b * 961;
    int ho = l / 31;
    int wo = l - ho * 31;

    const float* src = x + (size_t)b * 4096 + ho * 128 + wo * 2;
    float p[16];
    #pragma unroll
    for (int r = 0; r < 4; ++r){
        float2 v0 = *reinterpret_cast<const float2*>(src + r * 64);
        float2 v1 = *reinterpret_cast<const float2*>(src + r * 64 + 2);
        p[r*4+0] = v0.x; p[r*4+1] = v0.y; p[r*4+2] = v1.x; p[r*4+3] = v1.y;
    }

    float c00 = 0.f, c11 = 0.f, c01 = 0.f;
    #pragma unroll
    for (int i = 0; i < 16; ++i){
        float sq = p[i] * p[i];
        if (ringf(i) < 8){
            c00 += sq;
            #pragma unroll
            for (int j = 0; j < 16; ++j)
                if (ringf(j) == ringf(i) + 8) c01 += p[i] * p[j];
        } else {
            c11 += sq;
        }
    }
    float inv = 1.0f / (c00 + c11);

    float* dst = out + (size_t)b * (12 * 961) + l;
    #pragma unroll
    for (int j = 0; j < 12; ++j){
        float v = (scoef[j*3+0] * c00 + scoef[j*3+1] * c11 + scoef[j*3+2] * c01) * inv;
        dst[j * 961] = v;
    }
}

extern "C" void kernel_launch(void* const* d_in, const int* in_sizes, int n_in,
                              void* d_out, int out_size, void* d_ws, size_t ws_size,
                              hipStream_t stream)
{
    const float* x = (const float*)d_in[0];   // (B,1,64,64) f32
    const float* w = (const float*)d_in[1];   // (4,4,3) f32
    float* out  = (float*)d_out;              // (B,12,31,31) f32
    float* coef = (float*)d_ws;               // 36 floats scratch

    int B = in_sizes[0] / 4096;
    coef_kernel<<<1, 64, 0, stream>>>(w, coef);
    int total = B * 961;
    int blocks = (total + 255) / 256;
    qconv_kernel<<<blocks, 256, 0, stream>>>(x, coef, out, B);
}

// Round 2
// 67.814 us; speedup vs baseline: 1.0195x; 1.0195x over previous
//
#include <hip/hip_runtime.h>

// ---------------------------------------------------------------------------
// QConv2d collapses algebraically:
//   U = u0 (x) V  with V = u1(x)u2(x)u3  (wire 0 = MSB)
//   <psi| sigma_0 (x) I8 |psi> with psi = U P a  (a real, P = CNOT-ring perm)
//     = a^T [ P^T ( Re(u0^† sigma u0) (x) I8 ) P ] a
//     = alpha*c00 + beta*c11 + gamma*c01    (per (kernel, pauli))
// where c00 = sum_{i: f(i)<8} p_i^2, c11 = rest, c01 = sum p_{g(d)} p_{g(d+8)},
// (f = ring map), and a = p/||p|| so divide by n = ||p||^2.
// Coefs (36 floats) are recomputed per-block into LDS (cheap, graph-safe),
// eliminating the separate setup kernel + graph dependency that dominated
// the previous 69 us.
// ---------------------------------------------------------------------------

struct cplx { float re, im; };
__device__ inline cplx cmul(cplx a, cplx b){ return {a.re*b.re - a.im*b.im, a.re*b.im + a.im*b.re}; }
__device__ inline cplx cconj(cplx a){ return {a.re, -a.im}; }
__device__ inline cplx cadd(cplx a, cplx b){ return {a.re+b.re, a.im+b.im}; }

// CNOT ring map on basis index (wire 0 = MSB), exactly mirrors reference.
__host__ __device__ constexpr int ringf(int i){
    int s = i;
    for (int w = 0; w < 4; ++w){
        int c = w, t = (w + 1) & 3;
        if ((s >> (3 - c)) & 1) s ^= 1 << (3 - t);
    }
    return s;
}

// One thread per patch. B*961 threads; 961 = 31*31 output positions.
__global__ __launch_bounds__(256) void qconv_kernel(
    const float* __restrict__ x, const float* __restrict__ w,
    float* __restrict__ out, int B)
{
    __shared__ float scoef[36];
    {
        int t = threadIdx.x;
        if (t < 12) {
            int k = t / 3, o = t - 3 * (t / 3);
            float th = w[k*12 + 0], ph = w[k*12 + 1], om = w[k*12 + 2];
            float c = cosf(th * 0.5f), s = sinf(th * 0.5f);
            cplx u[2][2];
            u[0][0] = { c, 0.f };
            u[0][1] = { -cosf(om) * s, -sinf(om) * s };
            u[1][0] = {  cosf(ph) * s,  sinf(ph) * s };
            u[1][1] = {  cosf(ph + om) * c, sinf(ph + om) * c };
            cplx sig[2][2];
            if (o == 0){      sig[0][0]={0,0}; sig[0][1]={1,0};  sig[1][0]={1,0}; sig[1][1]={0,0}; }   // X
            else if (o == 1){ sig[0][0]={0,0}; sig[0][1]={0,-1}; sig[1][0]={0,1}; sig[1][1]={0,0}; }   // Y
            else {            sig[0][0]={1,0}; sig[0][1]={0,0};  sig[1][0]={0,0}; sig[1][1]={-1,0}; }  // Z
            cplx A[2][2];
            #pragma unroll
            for (int a = 0; a < 2; ++a)
                #pragma unroll
                for (int b = 0; b < 2; ++b){
                    cplx acc = {0.f, 0.f};
                    #pragma unroll
                    for (int ss = 0; ss < 2; ++ss)
                        #pragma unroll
                        for (int tt = 0; tt < 2; ++tt)
                            acc = cadd(acc, cmul(cmul(cconj(u[ss][a]), sig[ss][tt]), u[tt][b]));
                    A[a][b] = acc;
                }
            scoef[t*3 + 0] = A[0][0].re;
            scoef[t*3 + 1] = A[1][1].re;
            scoef[t*3 + 2] = 2.f * A[0][1].re;
        }
    }
    __syncthreads();

    int pid = blockIdx.x * 256 + threadIdx.x;
    if (pid >= B * 961) return;
    int b  = pid / 961;
    int l  = pid - b * 961;
    int ho = l / 31;
    int wo = l - ho * 31;

    const float* src = x + (size_t)b * 4096 + ho * 128 + wo * 2;
    float p[16];
    #pragma unroll
    for (int r = 0; r < 4; ++r){
        float2 v0 = *reinterpret_cast<const float2*>(src + r * 64);
        float2 v1 = *reinterpret_cast<const float2*>(src + r * 64 + 2);
        p[r*4+0] = v0.x; p[r*4+1] = v0.y; p[r*4+2] = v1.x; p[r*4+3] = v1.y;
    }

    float c00 = 0.f, c11 = 0.f, c01 = 0.f;
    #pragma unroll
    for (int i = 0; i < 16; ++i){
        float sq = p[i] * p[i];
        if (ringf(i) < 8){
            c00 += sq;
            #pragma unroll
            for (int j = 0; j < 16; ++j)
                if (ringf(j) == ringf(i) + 8) c01 += p[i] * p[j];
        } else {
            c11 += sq;
        }
    }
    float inv = 1.0f / (c00 + c11);

    float* dst = out + (size_t)b * (12 * 961) + l;
    #pragma unroll
    for (int j = 0; j < 12; ++j){
        float v = (scoef[j*3+0] * c00 + scoef[j*3+1] * c11 + scoef[j*3+2] * c01) * inv;
        dst[j * 961] = v;
    }
}

extern "C" void kernel_launch(void* const* d_in, const int* in_sizes, int n_in,
                              void* d_out, int out_size, void* d_ws, size_t ws_size,
                              hipStream_t stream)
{
    const float* x = (const float*)d_in[0];   // (B,1,64,64) f32
    const float* w = (const float*)d_in[1];   // (4,4,3) f32
    float* out = (float*)d_out;               // (B,12,31,31) f32

    int B = in_sizes[0] / 4096;
    int total = B * 961;
    int blocks = (total + 255) / 256;
    qconv_kernel<<<blocks, 256, 0, stream>>>(x, w, out, B);
}